// Round 6
// baseline (400.338 us; speedup 1.0000x reference)
//
#include <hip/hip_runtime.h>
#include <hip/hip_bf16.h>

#define EMB   1024
#define NHEAD 16
#define HDIM  64
#define BSZ   4
#define SEQ   2048
#define MROWS (BSZ*SEQ)     // 8192
#define NQKV  (3*EMB)       // 3072

typedef __bf16 bf16;
typedef __bf16 bf16v8 __attribute__((ext_vector_type(8)));
typedef float  f32v4  __attribute__((ext_vector_type(4)));

#define MFMA16(a,b,c) __builtin_amdgcn_mfma_f32_16x16x32_bf16((a),(b),(c),0,0,0)

__device__ __forceinline__ void gload_lds16(const bf16* g, bf16* l) {
  __builtin_amdgcn_global_load_lds((const __attribute__((address_space(1))) void*)g,
                                   (__attribute__((address_space(3))) void*)l,
                                   16, 0, 0);
}

// ---------------- scale reduction + ternarize + split ----------------

__global__ void zero2_kernel(float* p) { p[threadIdx.x] = 0.f; }

__global__ void abs_sum_kernel(const float* __restrict__ w, int n, float* out) {
  float s = 0.f;
  for (int i = blockIdx.x * blockDim.x + threadIdx.x; i < n; i += gridDim.x * blockDim.x)
    s += fabsf(w[i]);
  #pragma unroll
  for (int off = 32; off; off >>= 1) s += __shfl_down(s, off, 64);
  __shared__ float red[4];
  int lane = threadIdx.x & 63, wid = threadIdx.x >> 6;
  if (lane == 0) red[wid] = s;
  __syncthreads();
  if (threadIdx.x == 0) atomicAdd(out, red[0] + red[1] + red[2] + red[3]);
}

__global__ void ternarize_kernel(const float* __restrict__ w, int n,
                                 const float* __restrict__ sum, bf16* __restrict__ out) {
  int i = blockIdx.x * blockDim.x + threadIdx.x;
  if (i >= n) return;
  float scale = fmaxf(*sum / (float)n, 1e-8f);
  float t = rintf(w[i] / scale);          // RNE == jnp.round
  t = fmaxf(-1.f, fminf(1.f, t));
  out[i] = (bf16)t;                        // {-1,0,1} exact in bf16
}

__global__ void split_x_kernel(const float* __restrict__ x, bf16* __restrict__ xh,
                               bf16* __restrict__ xl, int n) {
  int i = blockIdx.x * blockDim.x + threadIdx.x;
  if (i >= n) return;
  float v = x[i];
  bf16 h = (bf16)v;
  xh[i] = h;
  xl[i] = (bf16)(v - (float)h);
}

// ---------------- QK GEMM (dual hi/lo MFMA, rows 0..2047 of w_qkv) ----------------
// q pre-scaled by 0.125*log2(e) so attn softmax works directly in log2 domain.
// Split from the old fused qkv kernel so the hot loop has no region branches.

__launch_bounds__(256, 2)
__global__ void gemm_qk_kernel(const bf16* __restrict__ xh, const bf16* __restrict__ xl,
                               const bf16* __restrict__ wt,
                               bf16* __restrict__ qh, bf16* __restrict__ ql,
                               bf16* __restrict__ kh, bf16* __restrict__ kl) {
  __shared__ __align__(16) bf16 Ah[128 * 64];
  __shared__ __align__(16) bf16 Al[128 * 64];
  __shared__ __align__(16) bf16 Bs[128 * 64];
  const int tid = threadIdx.x;
  const int lane = tid & 63, wid = tid >> 6;
  const int quad = lane >> 4, l16 = lane & 15;
  const int m0 = blockIdx.x * 128, n0 = blockIdx.y * 128;
  const int wm = (wid >> 1) * 64, wn = (wid & 1) * 64;
  f32v4 acc[4][4] = {};

  for (int kt = 0; kt < EMB / 64; ++kt) {
    __syncthreads();
    #pragma unroll
    for (int r = 0; r < 4; ++r) {
      int li = r * 256 + tid;
      int row = li >> 3, col = (li & 7) * 8;
      gload_lds16(xh + (size_t)(m0 + row) * EMB + kt * 64 + col, &Ah[li * 8]);
      gload_lds16(xl + (size_t)(m0 + row) * EMB + kt * 64 + col, &Al[li * 8]);
      gload_lds16(wt + (size_t)(n0 + row) * EMB + kt * 64 + col, &Bs[li * 8]);
    }
    __syncthreads();
    #pragma unroll
    for (int kk = 0; kk < 2; ++kk) {
      bf16v8 af[4], alf[4], bfr[4];
      #pragma unroll
      for (int i = 0; i < 4; ++i) {
        af[i]  = *(const bf16v8*)&Ah[(wm + i * 16 + l16) * 64 + kk * 32 + quad * 8];
        alf[i] = *(const bf16v8*)&Al[(wm + i * 16 + l16) * 64 + kk * 32 + quad * 8];
        bfr[i] = *(const bf16v8*)&Bs[(wn + i * 16 + l16) * 64 + kk * 32 + quad * 8];
      }
      #pragma unroll
      for (int i = 0; i < 4; ++i)
        #pragma unroll
        for (int j = 0; j < 4; ++j) {
          acc[i][j] = MFMA16(af[i],  bfr[j], acc[i][j]);
          acc[i][j] = MFMA16(alf[i], bfr[j], acc[i][j]);
        }
    }
  }
  const float QSCALE = 0.18033688011112042f;   // 0.125 * log2(e)
  const bool qreg = (n0 < EMB);                 // block-uniform
  #pragma unroll
  for (int i = 0; i < 4; ++i)
    #pragma unroll
    for (int j = 0; j < 4; ++j)
      #pragma unroll
      for (int r = 0; r < 4; ++r) {
        int m = m0 + wm + i * 16 + quad * 4 + r;
        int n = n0 + wn + j * 16 + l16;
        float c = acc[i][j][r];
        int b = m >> 11, t = m & (SEQ - 1);
        int c1 = n & 1023, h = c1 >> 6, d = c1 & 63;
        size_t idx = (((size_t)(b * NHEAD + h) * SEQ + t) << 6) + d;
        if (qreg) { float cs = c * QSCALE; bf16 hi = (bf16)cs; qh[idx] = hi; ql[idx] = (bf16)(cs - (float)hi); }
        else      { bf16 hi = (bf16)c;  kh[idx] = hi; kl[idx] = (bf16)(c - (float)hi); }
      }
}

// ---------------- V GEMM (single MFMA, rows 2048..3071 of w_qkv) ----------------

__launch_bounds__(256, 2)
__global__ void gemm_v_kernel(const bf16* __restrict__ xh, const bf16* __restrict__ wt2,
                              bf16* __restrict__ vv) {
  __shared__ __align__(16) bf16 Ah[128 * 64];
  __shared__ __align__(16) bf16 Bs[128 * 64];
  const int tid = threadIdx.x;
  const int lane = tid & 63, wid = tid >> 6;
  const int quad = lane >> 4, l16 = lane & 15;
  const int m0 = blockIdx.x * 128, n0 = blockIdx.y * 128;
  const int wm = (wid >> 1) * 64, wn = (wid & 1) * 64;
  f32v4 acc[4][4] = {};

  for (int kt = 0; kt < EMB / 64; ++kt) {
    __syncthreads();
    #pragma unroll
    for (int r = 0; r < 4; ++r) {
      int li = r * 256 + tid;
      int row = li >> 3, col = (li & 7) * 8;
      gload_lds16(xh  + (size_t)(m0 + row) * EMB + kt * 64 + col, &Ah[li * 8]);
      gload_lds16(wt2 + (size_t)(n0 + row) * EMB + kt * 64 + col, &Bs[li * 8]);
    }
    __syncthreads();
    #pragma unroll
    for (int kk = 0; kk < 2; ++kk) {
      bf16v8 af[4], bfr[4];
      #pragma unroll
      for (int i = 0; i < 4; ++i) {
        af[i]  = *(const bf16v8*)&Ah[(wm + i * 16 + l16) * 64 + kk * 32 + quad * 8];
        bfr[i] = *(const bf16v8*)&Bs[(wn + i * 16 + l16) * 64 + kk * 32 + quad * 8];
      }
      #pragma unroll
      for (int i = 0; i < 4; ++i)
        #pragma unroll
        for (int j = 0; j < 4; ++j)
          acc[i][j] = MFMA16(af[i], bfr[j], acc[i][j]);
    }
  }
  #pragma unroll
  for (int i = 0; i < 4; ++i)
    #pragma unroll
    for (int j = 0; j < 4; ++j)
      #pragma unroll
      for (int r = 0; r < 4; ++r) {
        int m = m0 + wm + i * 16 + quad * 4 + r;
        int n = n0 + wn + j * 16 + l16;
        int b = m >> 11, t = m & (SEQ - 1);
        int h = n >> 6, d = n & 63;
        size_t idx = (((size_t)(b * NHEAD + h) * SEQ + t) << 6) + d;
        vv[idx] = (bf16)acc[i][j][r];
      }
}

// ---------------- V transpose: [B,H,T,D] -> [B,H,D,T] ----------------

__global__ void transpose_v_kernel(const bf16* __restrict__ v, bf16* __restrict__ vt) {
  __shared__ bf16 tile[64 * 72];
  const int tid = threadIdx.x;
  const int bh = blockIdx.y, t0 = blockIdx.x * 64;
  const size_t base = (size_t)bh * SEQ * HDIM;
  #pragma unroll
  for (int r = 0; r < 2; ++r) {
    int li = r * 256 + tid;
    int row = li >> 3, col = (li & 7) * 8;
    bf16v8 val = *(const bf16v8*)(v + base + (size_t)(t0 + row) * HDIM + col);
    #pragma unroll
    for (int j = 0; j < 8; ++j) tile[(col + j) * 72 + row] = val[j];
  }
  __syncthreads();
  #pragma unroll
  for (int r = 0; r < 2; ++r) {
    int li = r * 256 + tid;
    int drow = li >> 3, tcol = (li & 7) * 8;
    bf16v8 val;
    #pragma unroll
    for (int j = 0; j < 8; ++j) val[j] = tile[drow * 72 + tcol + j];
    *(bf16v8*)(vt + base + (size_t)drow * SEQ + t0 + tcol) = val;
  }
}

// ---------------- Flash attention v6 ----------------
// = v5 (uniform pairing, overlay, ones-column row-sum, log2 scores) + K/V
// DOUBLE-BUFFER with ONE barrier per tile: loads for tile i+1 are issued
// right after barrier_i and drain (warm) at barrier_{i+1}, a full compute
// phase later. Round-5 structure drained cold vmcnt(0) at the 2nd barrier
// of every tile; occupancy is grid-capped at 2 blocks/CU so waves can't
// hide it. LDS: 2x24 KB bufs + 17.4 KB P = 65 KB (Q overlays bufs).

__launch_bounds__(512, 4)
__global__ void attn_kernel(const bf16* __restrict__ qh, const bf16* __restrict__ ql,
                            const bf16* __restrict__ kh, const bf16* __restrict__ kl,
                            const bf16* __restrict__ vt, bf16* __restrict__ o) {
  __shared__ __align__(16) char smem[66560];
  // buf b at smem + b*24576: Kh [0,8K) | Kl [8K,16K) | Vt [16K,24K)
  bf16* Qh = (bf16*)smem;               // Q phase overlay (dead after frag read)
  bf16* Ql = (bf16*)(smem + 16384);
  bf16* Pw = (bf16*)(smem + 49152);     // 8 waves * 16*68*2 = 17408 B
  const int tid = threadIdx.x;
  const int lane = tid & 63, wid = tid >> 6;
  const int quad = lane >> 4, l16 = lane & 15;
  const int xs = l16 & 7;
  const int pair = blockIdx.x;          // 0..7
  const int bh = blockIdx.y;
  const size_t base = (size_t)bh * SEQ * HDIM;

  const int srow = tid >> 3, scg = (tid & 7) ^ (srow & 7);
  auto stage_kv = [&](char* dst, int k0) {
    gload_lds16(kh + base + (size_t)(k0 + srow) * HDIM + scg * 8, (bf16*)dst + (size_t)tid * 8);
    gload_lds16(kl + base + (size_t)(k0 + srow) * HDIM + scg * 8, (bf16*)(dst + 8192) + (size_t)tid * 8);
    gload_lds16(vt + base + (size_t)srow * SEQ + k0 + scg * 8,    (bf16*)(dst + 16384) + (size_t)tid * 8);
  };

  bf16v8 ones_f;
  {
    bf16 v1 = (l16 == 0) ? (bf16)1.0f : (bf16)0.0f;
    #pragma unroll
    for (int j = 0; j < 8; ++j) ones_f[j] = v1;
  }
  const int b = bh >> 4, h = bh & 15;

  for (int phase = 0; phase < 2; ++phase) {
    const int qt = phase ? (7 - pair) : (8 + pair);
    const int q0 = qt * 128;

    __syncthreads();                    // prior phase's LDS readers done
    // stage Q (hi+lo), swizzled
    #pragma unroll
    for (int r = 0; r < 2; ++r) {
      int li = r * 512 + tid;
      int row = li >> 3, cg = (li & 7) ^ (row & 7);
      gload_lds16(qh + base + (size_t)(q0 + row) * HDIM + cg * 8, &Qh[li * 8]);
      gload_lds16(ql + base + (size_t)(q0 + row) * HDIM + cg * 8, &Ql[li * 8]);
    }
    __syncthreads();
    bf16v8 qhf[2], qlf[2];
    #pragma unroll
    for (int kk = 0; kk < 2; ++kk) {
      int off = (wid * 16 + l16) * 64 + (((kk << 2) | quad) ^ xs) * 8;
      qhf[kk] = *(const bf16v8*)&Qh[off];
      qlf[kk] = *(const bf16v8*)&Ql[off];
    }
    __syncthreads();                    // all waves hold Q frags; bufs free

    f32v4 oacc[4] = {};
    f32v4 lacc = {};
    float mrow[4];
    #pragma unroll
    for (int r = 0; r < 4; ++r) mrow[r] = -1e30f;

    const int qrow_hi = q0 + wid * 16 + 15;     // wave-uniform causal limit
    const int ntiles = 2 * qt + 2;

    stage_kv(smem, 0);                  // preload tile 0 -> buf0 (cold drain once)

    for (int ktile = 0; ktile < ntiles; ++ktile) {
      char* cb = smem + (size_t)((ktile & 1) * 24576);
      char* nb = smem + (size_t)(((ktile + 1) & 1) * 24576);
      __syncthreads();                  // tile ktile staged (all waves); prev buf free
      if (ktile + 1 < ntiles) stage_kv(nb, (ktile + 1) * 64);   // prefetch, in flight
      const int k0 = ktile * 64;
      if (k0 > qrow_hi) continue;       // fully-masked tile for this wave

      bf16* Kh_ = (bf16*)cb;
      bf16* Kl_ = (bf16*)(cb + 8192);
      bf16* Vt_ = (bf16*)(cb + 16384);

      f32v4 sacc[4] = {};
      #pragma unroll
      for (int kk = 0; kk < 2; ++kk) {
        const int co = (((kk << 2) | quad) ^ xs) * 8;
        bf16v8 khf[4], klf[4];
        #pragma unroll
        for (int nt = 0; nt < 4; ++nt) {
          khf[nt] = *(const bf16v8*)&Kh_[(nt * 16 + l16) * 64 + co];
          klf[nt] = *(const bf16v8*)&Kl_[(nt * 16 + l16) * 64 + co];
        }
        #pragma unroll
        for (int nt = 0; nt < 4; ++nt) {
          sacc[nt] = MFMA16(qhf[kk], khf[nt], sacc[nt]);
          sacc[nt] = MFMA16(qhf[kk], klf[nt], sacc[nt]);
          sacc[nt] = MFMA16(qlf[kk], khf[nt], sacc[nt]);
        }
      }

      // mask (scores already in log2 domain)
      const int qrow_base = q0 + wid * 16 + quad * 4;
      #pragma unroll
      for (int nt = 0; nt < 4; ++nt) {
        int key = k0 + nt * 16 + l16;
        #pragma unroll
        for (int r = 0; r < 4; ++r)
          if (key > qrow_base + r) sacc[nt][r] = -1e30f;
      }
      float mnew[4], alpha[4];
      #pragma unroll
      for (int r = 0; r < 4; ++r) {
        float mx = fmaxf(fmaxf(sacc[0][r], sacc[1][r]), fmaxf(sacc[2][r], sacc[3][r]));
        #pragma unroll
        for (int off = 8; off; off >>= 1) mx = fmaxf(mx, __shfl_xor(mx, off, 64));
        mnew[r] = fmaxf(mrow[r], mx);
        alpha[r] = __builtin_amdgcn_exp2f(mrow[r] - mnew[r]);
        mrow[r] = mnew[r];
      }
      bf16* pwave = Pw + wid * (16 * 68);
      #pragma unroll
      for (int nt = 0; nt < 4; ++nt)
        #pragma unroll
        for (int r = 0; r < 4; ++r)
          pwave[(quad * 4 + r) * 68 + nt * 16 + l16] =
              (bf16)__builtin_amdgcn_exp2f(sacc[nt][r] - mnew[r]);
      #pragma unroll
      for (int r = 0; r < 4; ++r) {
        lacc[r] *= alpha[r];
        #pragma unroll
        for (int dt = 0; dt < 4; ++dt) oacc[dt][r] *= alpha[r];
      }

      // PV + row-sum (ones-column): A = P (wave-private LDS slice)
      #pragma unroll
      for (int kk = 0; kk < 2; ++kk) {
        bf16v8 pf = *(const bf16v8*)&pwave[l16 * 68 + kk * 32 + quad * 8];
        const int co = (((kk << 2) | quad) ^ xs) * 8;
        lacc = MFMA16(pf, ones_f, lacc);
        #pragma unroll
        for (int dt = 0; dt < 4; ++dt) {
          bf16v8 vf = *(const bf16v8*)&Vt_[(dt * 16 + l16) * 64 + co];
          oacc[dt] = MFMA16(pf, vf, oacc[dt]);
        }
      }
    }

    // row-sum lives in column 0 (lane l16==0 of each quad) -> broadcast
    float lrow[4];
    #pragma unroll
    for (int r = 0; r < 4; ++r) lrow[r] = __shfl(lacc[r], lane & 48, 64);

    #pragma unroll
    for (int dt = 0; dt < 4; ++dt)
      #pragma unroll
      for (int r = 0; r < 4; ++r) {
        int q = q0 + wid * 16 + quad * 4 + r;
        int d = dt * 16 + l16;
        float val = oacc[dt][r] / lrow[r];
        o[((size_t)(b * SEQ + q)) * EMB + h * HDIM + d] = (bf16)val;
      }
  }
}

// ---------------- out projection (unchanged) ----------------

__launch_bounds__(256, 2)
__global__ void gemm_out_kernel(const bf16* __restrict__ oin, const bf16* __restrict__ wt,
                                float* __restrict__ out) {
  __shared__ __align__(16) bf16 As_[128 * 64];
  __shared__ __align__(16) bf16 Bs_[128 * 64];
  const int tid = threadIdx.x;
  const int lane = tid & 63, wid = tid >> 6;
  const int quad = lane >> 4, l16 = lane & 15;
  const int m0 = blockIdx.x * 128, n0 = blockIdx.y * 128;
  const int wm = (wid >> 1) * 64, wn = (wid & 1) * 64;
  f32v4 acc[4][4] = {};

  for (int kt = 0; kt < EMB / 64; ++kt) {
    __syncthreads();
    #pragma unroll
    for (int r = 0; r < 4; ++r) {
      int li = r * 256 + tid;
      int row = li >> 3, col = (li & 7) * 8;
      gload_lds16(oin + (size_t)(m0 + row) * EMB + kt * 64 + col, &As_[li * 8]);
      gload_lds16(wt  + (size_t)(n0 + row) * EMB + kt * 64 + col, &Bs_[li * 8]);
    }
    __syncthreads();
    #pragma unroll
    for (int kk = 0; kk < 2; ++kk) {
      bf16v8 af[4], bfr[4];
      #pragma unroll
      for (int i = 0; i < 4; ++i) {
        af[i]  = *(const bf16v8*)&As_[(wm + i * 16 + l16) * 64 + kk * 32 + quad * 8];
        bfr[i] = *(const bf16v8*)&Bs_[(wn + i * 16 + l16) * 64 + kk * 32 + quad * 8];
      }
      #pragma unroll
      for (int i = 0; i < 4; ++i)
        #pragma unroll
        for (int j = 0; j < 4; ++j)
          acc[i][j] = MFMA16(af[i], bfr[j], acc[i][j]);
    }
  }
  #pragma unroll
  for (int i = 0; i < 4; ++i)
    #pragma unroll
    for (int j = 0; j < 4; ++j)
      #pragma unroll
      for (int r = 0; r < 4; ++r) {
        int m = m0 + wm + i * 16 + quad * 4 + r;
        int n = n0 + wn + j * 16 + l16;
        out[(size_t)m * EMB + n] = acc[i][j][r];
      }
}

// ---------------- launch ----------------

extern "C" void kernel_launch(void* const* d_in, const int* in_sizes, int n_in,
                              void* d_out, int out_size, void* d_ws, size_t ws_size,
                              hipStream_t stream) {
  const float* x     = (const float*)d_in[0];
  const float* w_qkv = (const float*)d_in[1];
  const float* w_out = (const float*)d_in[2];
  float* out = (float*)d_out;
  char* ws = (char*)d_ws;

  const size_t SZ = (size_t)MROWS * EMB * sizeof(bf16);   // 16.78 MB
  size_t off = 0;
  float* sums = (float*)ws;            off = 256;
  bf16* wq_t = (bf16*)(ws + off);      off += (size_t)NQKV * EMB * sizeof(bf16);
  bf16* wo_t = (bf16*)(ws + off);      off += (size_t)EMB * EMB * sizeof(bf16);
  bf16* xh   = (bf16*)(ws + off);      off += SZ;
  bf16* xl   = (bf16*)(ws + off);      off += SZ;
  bf16* qh   = (bf16*)(ws + off);      off += SZ;
  bf16* ql   = (bf16*)(ws + off);      off += SZ;
  bf16* kh   = (bf16*)(ws + off);      off += SZ;
  bf16* kl   = (bf16*)(ws + off);      off += SZ;
  bf16* vv   = (bf16*)(ws + off);      off += SZ;
  bf16* vt   = xh;   // x dead after qkv GEMMs -> reuse
  bf16* ob   = xl;   // attention output (bf16), reuse
  (void)in_sizes; (void)n_in; (void)out_size; (void)ws_size;

  zero2_kernel<<<1, 2, 0, stream>>>(sums);
  abs_sum_kernel<<<256, 256, 0, stream>>>(w_qkv, NQKV * EMB, &sums[0]);
  abs_sum_kernel<<<256, 256, 0, stream>>>(w_out, EMB * EMB, &sums[1]);
  ternarize_kernel<<<(NQKV * EMB) / 256, 256, 0, stream>>>(w_qkv, NQKV * EMB, &sums[0], wq_t);
  ternarize_kernel<<<(EMB * EMB) / 256, 256, 0, stream>>>(w_out, EMB * EMB, &sums[1], wo_t);
  split_x_kernel<<<(MROWS * EMB) / 256, 256, 0, stream>>>(x, xh, xl, MROWS * EMB);
  gemm_qk_kernel<<<dim3(MROWS / 128, 16), 256, 0, stream>>>(xh, xl, wq_t, qh, ql, kh, kl);
  gemm_v_kernel<<<dim3(MROWS / 128, 8), 256, 0, stream>>>(xh, wq_t + (size_t)2 * EMB * EMB, vv);
  transpose_v_kernel<<<dim3(SEQ / 64, BSZ * NHEAD), 256, 0, stream>>>(vv, vt);
  attn_kernel<<<dim3(8, BSZ * NHEAD), 512, 0, stream>>>(qh, ql, kh, kl, vt, ob);
  gemm_out_kernel<<<dim3(MROWS / 128, EMB / 128), 256, 0, stream>>>(ob, wo_t, out);
}

// Round 7
// 355.944 us; speedup vs baseline: 1.1247x; 1.1247x over previous
//
#include <hip/hip_runtime.h>
#include <hip/hip_bf16.h>

#define EMB   1024
#define NHEAD 16
#define HDIM  64
#define BSZ   4
#define SEQ   2048
#define MROWS (BSZ*SEQ)     // 8192
#define NQKV  (3*EMB)       // 3072

typedef __bf16 bf16;
typedef __bf16 bf16v8 __attribute__((ext_vector_type(8)));
typedef float  f32v4  __attribute__((ext_vector_type(4)));
typedef int    i32v4  __attribute__((ext_vector_type(4)));

#define MFMA16(a,b,c)  __builtin_amdgcn_mfma_f32_16x16x32_bf16((a),(b),(c),0,0,0)
#define MFMAI8(a,b,c)  __builtin_amdgcn_mfma_i32_16x16x64_i8((a),(b),(c),0,0,0)

__device__ __forceinline__ void gload_lds16(const void* g, void* l) {
  __builtin_amdgcn_global_load_lds((const __attribute__((address_space(1))) void*)g,
                                   (__attribute__((address_space(3))) void*)l,
                                   16, 0, 0);
}

// ---------------- scale reduction + ternarize + quantize ----------------

__global__ void zero2_kernel(float* p) { p[threadIdx.x] = 0.f; }

__global__ void abs_sum_kernel(const float* __restrict__ w, int n, float* out) {
  float s = 0.f;
  for (int i = blockIdx.x * blockDim.x + threadIdx.x; i < n; i += gridDim.x * blockDim.x)
    s += fabsf(w[i]);
  #pragma unroll
  for (int off = 32; off; off >>= 1) s += __shfl_down(s, off, 64);
  __shared__ float red[4];
  int lane = threadIdx.x & 63, wid = threadIdx.x >> 6;
  if (lane == 0) red[wid] = s;
  __syncthreads();
  if (threadIdx.x == 0) atomicAdd(out, red[0] + red[1] + red[2] + red[3]);
}

// ternary weights as i8 (exact)
__global__ void ternarize_i8_kernel(const float* __restrict__ w, int n,
                                    const float* __restrict__ sum, char* __restrict__ out) {
  int i = blockIdx.x * blockDim.x + threadIdx.x;
  if (i >= n) return;
  float scale = fmaxf(*sum / (float)n, 1e-8f);
  float t = rintf(w[i] / scale);          // RNE == jnp.round
  t = fmaxf(-1.f, fminf(1.f, t));
  out[i] = (char)(int)t;
}

// ternary weights as bf16 (for the bf16 out-projection GEMM)
__global__ void ternarize_bf16_kernel(const float* __restrict__ w, int n,
                                      const float* __restrict__ sum, bf16* __restrict__ out) {
  int i = blockIdx.x * blockDim.x + threadIdx.x;
  if (i >= n) return;
  float scale = fmaxf(*sum / (float)n, 1e-8f);
  float t = rintf(w[i] / scale);
  t = fmaxf(-1.f, fminf(1.f, t));
  out[i] = (bf16)t;
}

// x -> two i8 planes: x ~= p1/16 + p2/4096 (|err| <= 2.4e-4; exact i32 MFMA accum)
__global__ void quant_x_kernel(const float* __restrict__ x, char* __restrict__ p1,
                               char* __restrict__ p2, int n) {
  int i = blockIdx.x * blockDim.x + threadIdx.x;
  if (i >= n) return;
  float v = x[i];
  float q1 = fminf(fmaxf(rintf(v * 16.f), -127.f), 127.f);
  float r = v - q1 * 0.0625f;
  float q2 = fminf(fmaxf(rintf(r * 4096.f), -127.f), 127.f);
  p1[i] = (char)(int)q1;
  p2[i] = (char)(int)q2;
}

// ---------------- fused QKV GEMM, dual-plane i8 ----------------
// C[m][n] = (1/16)*sum p1[m][k]*w[n][k] + (1/4096)*sum p2[m][k]*w[n][k]
// mfma_i32_16x16x64_i8: 2x K per inst vs bf16, exact i32 accumulation ->
// half the MFMA instructions and half the staging bytes of dual-bf16.
// Swizzle: 16B chunk c of row r stored at slot c^((r>>1)&3) -> frag reads 2-way (free).
// q pre-scaled by 0.125*log2(e); q,k written as bf16 hi/lo; v single bf16.

__launch_bounds__(256, 2)
__global__ void gemm_qkv_kernel(const char* __restrict__ xq1, const char* __restrict__ xq2,
                                const char* __restrict__ w8,
                                bf16* __restrict__ qh, bf16* __restrict__ ql,
                                bf16* __restrict__ kh, bf16* __restrict__ kl,
                                bf16* __restrict__ vv) {
  __shared__ __align__(16) char A1[128 * 64];
  __shared__ __align__(16) char A2[128 * 64];
  __shared__ __align__(16) char Bs[128 * 64];
  const int tid = threadIdx.x;
  const int lane = tid & 63, wid = tid >> 6;
  const int quad = lane >> 4, l16 = lane & 15;
  const int m0 = blockIdx.x * 128, n0 = blockIdx.y * 128;
  const int wm = (wid >> 1) * 64, wn = (wid & 1) * 64;
  const int asw = (l16 >> 1) & 3;         // fragment-read swizzle
  i32v4 acc1[4][4] = {};
  i32v4 acc2[4][4] = {};

  for (int kt = 0; kt < EMB / 64; ++kt) {
    __syncthreads();
    #pragma unroll
    for (int r = 0; r < 2; ++r) {
      int li = r * 256 + tid;
      int row = li >> 2, cs = li & 3;
      int cg = cs ^ ((row >> 1) & 3);
      gload_lds16(xq1 + (size_t)(m0 + row) * EMB + kt * 64 + cg * 16, &A1[li * 16]);
      gload_lds16(xq2 + (size_t)(m0 + row) * EMB + kt * 64 + cg * 16, &A2[li * 16]);
      gload_lds16(w8  + (size_t)(n0 + row) * EMB + kt * 64 + cg * 16, &Bs[li * 16]);
    }
    __syncthreads();
    i32v4 af1[4], af2[4], bfr[4];
    #pragma unroll
    for (int i = 0; i < 4; ++i) {
      int arow = wm + i * 16 + l16;
      int off = arow * 64 + ((quad ^ asw) * 16);
      af1[i] = *(const i32v4*)&A1[off];
      af2[i] = *(const i32v4*)&A2[off];
      int brow = wn + i * 16 + l16;
      bfr[i] = *(const i32v4*)&Bs[brow * 64 + ((quad ^ asw) * 16)];
    }
    #pragma unroll
    for (int i = 0; i < 4; ++i)
      #pragma unroll
      for (int j = 0; j < 4; ++j) {
        acc1[i][j] = MFMAI8(af1[i], bfr[j], acc1[i][j]);
        acc2[i][j] = MFMAI8(af2[i], bfr[j], acc2[i][j]);
      }
  }
  const float S1 = 0.0625f, S2 = 1.f / 4096.f;
  const float QSCALE = 0.18033688011112042f;   // 0.125 * log2(e)
  #pragma unroll
  for (int i = 0; i < 4; ++i)
    #pragma unroll
    for (int j = 0; j < 4; ++j)
      #pragma unroll
      for (int r = 0; r < 4; ++r) {
        int m = m0 + wm + i * 16 + quad * 4 + r;
        int n = n0 + wn + j * 16 + l16;
        float c = (float)acc1[i][j][r] * S1 + (float)acc2[i][j][r] * S2;
        int b = m >> 11, t = m & (SEQ - 1);
        int region = n >> 10, c1 = n & 1023, h = c1 >> 6, d = c1 & 63;
        size_t idx = (((size_t)(b * NHEAD + h) * SEQ + t) << 6) + d;
        if (region == 0)      { float cs = c * QSCALE; bf16 hi = (bf16)cs; qh[idx] = hi; ql[idx] = (bf16)(cs - (float)hi); }
        else if (region == 1) { bf16 hi = (bf16)c; kh[idx] = hi; kl[idx] = (bf16)(c - (float)hi); }
        else                  { vv[idx] = (bf16)c; }
      }
}

// ---------------- V transpose: [B,H,T,D] -> [B,H,D,T] ----------------

__global__ void transpose_v_kernel(const bf16* __restrict__ v, bf16* __restrict__ vt) {
  __shared__ bf16 tile[64 * 72];
  const int tid = threadIdx.x;
  const int bh = blockIdx.y, t0 = blockIdx.x * 64;
  const size_t base = (size_t)bh * SEQ * HDIM;
  #pragma unroll
  for (int r = 0; r < 2; ++r) {
    int li = r * 256 + tid;
    int row = li >> 3, col = (li & 7) * 8;
    bf16v8 val = *(const bf16v8*)(v + base + (size_t)(t0 + row) * HDIM + col);
    #pragma unroll
    for (int j = 0; j < 8; ++j) tile[(col + j) * 72 + row] = val[j];
  }
  __syncthreads();
  #pragma unroll
  for (int r = 0; r < 2; ++r) {
    int li = r * 256 + tid;
    int drow = li >> 3, tcol = (li & 7) * 8;
    bf16v8 val;
    #pragma unroll
    for (int j = 0; j < 8; ++j) val[j] = tile[drow * 72 + tcol + j];
    *(bf16v8*)(vt + base + (size_t)drow * SEQ + t0 + tcol) = val;
  }
}

// ---------------- Flash attention (unchanged from round 6) ----------------

__launch_bounds__(512, 4)
__global__ void attn_kernel(const bf16* __restrict__ qh, const bf16* __restrict__ ql,
                            const bf16* __restrict__ kh, const bf16* __restrict__ kl,
                            const bf16* __restrict__ vt, bf16* __restrict__ o) {
  __shared__ __align__(16) char smem[66560];
  // buf b at smem + b*24576: Kh [0,8K) | Kl [8K,16K) | Vt [16K,24K)
  bf16* Qh = (bf16*)smem;               // Q phase overlay (dead after frag read)
  bf16* Ql = (bf16*)(smem + 16384);
  bf16* Pw = (bf16*)(smem + 49152);     // 8 waves * 16*68*2 = 17408 B
  const int tid = threadIdx.x;
  const int lane = tid & 63, wid = tid >> 6;
  const int quad = lane >> 4, l16 = lane & 15;
  const int xs = l16 & 7;
  const int pair = blockIdx.x;          // 0..7
  const int bh = blockIdx.y;
  const size_t base = (size_t)bh * SEQ * HDIM;

  const int srow = tid >> 3, scg = (tid & 7) ^ (srow & 7);
  auto stage_kv = [&](char* dst, int k0) {
    gload_lds16(kh + base + (size_t)(k0 + srow) * HDIM + scg * 8, (bf16*)dst + (size_t)tid * 8);
    gload_lds16(kl + base + (size_t)(k0 + srow) * HDIM + scg * 8, (bf16*)(dst + 8192) + (size_t)tid * 8);
    gload_lds16(vt + base + (size_t)srow * SEQ + k0 + scg * 8,    (bf16*)(dst + 16384) + (size_t)tid * 8);
  };

  bf16v8 ones_f;
  {
    bf16 v1 = (l16 == 0) ? (bf16)1.0f : (bf16)0.0f;
    #pragma unroll
    for (int j = 0; j < 8; ++j) ones_f[j] = v1;
  }
  const int b = bh >> 4, h = bh & 15;

  for (int phase = 0; phase < 2; ++phase) {
    const int qt = phase ? (7 - pair) : (8 + pair);
    const int q0 = qt * 128;

    __syncthreads();                    // prior phase's LDS readers done
    // stage Q (hi+lo), swizzled
    #pragma unroll
    for (int r = 0; r < 2; ++r) {
      int li = r * 512 + tid;
      int row = li >> 3, cg = (li & 7) ^ (row & 7);
      gload_lds16(qh + base + (size_t)(q0 + row) * HDIM + cg * 8, &Qh[li * 8]);
      gload_lds16(ql + base + (size_t)(q0 + row) * HDIM + cg * 8, &Ql[li * 8]);
    }
    __syncthreads();
    bf16v8 qhf[2], qlf[2];
    #pragma unroll
    for (int kk = 0; kk < 2; ++kk) {
      int off = (wid * 16 + l16) * 64 + (((kk << 2) | quad) ^ xs) * 8;
      qhf[kk] = *(const bf16v8*)&Qh[off];
      qlf[kk] = *(const bf16v8*)&Ql[off];
    }
    __syncthreads();                    // all waves hold Q frags; bufs free

    f32v4 oacc[4] = {};
    f32v4 lacc = {};
    float mrow[4];
    #pragma unroll
    for (int r = 0; r < 4; ++r) mrow[r] = -1e30f;

    const int qrow_hi = q0 + wid * 16 + 15;     // wave-uniform causal limit
    const int ntiles = 2 * qt + 2;

    stage_kv(smem, 0);                  // preload tile 0 -> buf0 (cold drain once)

    for (int ktile = 0; ktile < ntiles; ++ktile) {
      char* cb = smem + (size_t)((ktile & 1) * 24576);
      char* nb = smem + (size_t)(((ktile + 1) & 1) * 24576);
      __syncthreads();                  // tile ktile staged (all waves); prev buf free
      if (ktile + 1 < ntiles) stage_kv(nb, (ktile + 1) * 64);   // prefetch, in flight
      const int k0 = ktile * 64;
      if (k0 > qrow_hi) continue;       // fully-masked tile for this wave

      bf16* Kh_ = (bf16*)cb;
      bf16* Kl_ = (bf16*)(cb + 8192);
      bf16* Vt_ = (bf16*)(cb + 16384);

      f32v4 sacc[4] = {};
      #pragma unroll
      for (int kk = 0; kk < 2; ++kk) {
        const int co = (((kk << 2) | quad) ^ xs) * 8;
        bf16v8 khf[4], klf[4];
        #pragma unroll
        for (int nt = 0; nt < 4; ++nt) {
          khf[nt] = *(const bf16v8*)&Kh_[(nt * 16 + l16) * 64 + co];
          klf[nt] = *(const bf16v8*)&Kl_[(nt * 16 + l16) * 64 + co];
        }
        #pragma unroll
        for (int nt = 0; nt < 4; ++nt) {
          sacc[nt] = MFMA16(qhf[kk], khf[nt], sacc[nt]);
          sacc[nt] = MFMA16(qhf[kk], klf[nt], sacc[nt]);
          sacc[nt] = MFMA16(qlf[kk], khf[nt], sacc[nt]);
        }
      }

      // mask (scores already in log2 domain)
      const int qrow_base = q0 + wid * 16 + quad * 4;
      #pragma unroll
      for (int nt = 0; nt < 4; ++nt) {
        int key = k0 + nt * 16 + l16;
        #pragma unroll
        for (int r = 0; r < 4; ++r)
          if (key > qrow_base + r) sacc[nt][r] = -1e30f;
      }
      float mnew[4], alpha[4];
      #pragma unroll
      for (int r = 0; r < 4; ++r) {
        float mx = fmaxf(fmaxf(sacc[0][r], sacc[1][r]), fmaxf(sacc[2][r], sacc[3][r]));
        #pragma unroll
        for (int off = 8; off; off >>= 1) mx = fmaxf(mx, __shfl_xor(mx, off, 64));
        mnew[r] = fmaxf(mrow[r], mx);
        alpha[r] = __builtin_amdgcn_exp2f(mrow[r] - mnew[r]);
        mrow[r] = mnew[r];
      }
      bf16* pwave = Pw + wid * (16 * 68);
      #pragma unroll
      for (int nt = 0; nt < 4; ++nt)
        #pragma unroll
        for (int r = 0; r < 4; ++r)
          pwave[(quad * 4 + r) * 68 + nt * 16 + l16] =
              (bf16)__builtin_amdgcn_exp2f(sacc[nt][r] - mnew[r]);
      #pragma unroll
      for (int r = 0; r < 4; ++r) {
        lacc[r] *= alpha[r];
        #pragma unroll
        for (int dt = 0; dt < 4; ++dt) oacc[dt][r] *= alpha[r];
      }

      // PV + row-sum (ones-column): A = P (wave-private LDS slice)
      #pragma unroll
      for (int kk = 0; kk < 2; ++kk) {
        bf16v8 pf = *(const bf16v8*)&pwave[l16 * 68 + kk * 32 + quad * 8];
        const int co = (((kk << 2) | quad) ^ xs) * 8;
        lacc = MFMA16(pf, ones_f, lacc);
        #pragma unroll
        for (int dt = 0; dt < 4; ++dt) {
          bf16v8 vf = *(const bf16v8*)&Vt_[(dt * 16 + l16) * 64 + co];
          oacc[dt] = MFMA16(pf, vf, oacc[dt]);
        }
      }
    }

    // row-sum lives in column 0 (lane l16==0 of each quad) -> broadcast
    float lrow[4];
    #pragma unroll
    for (int r = 0; r < 4; ++r) lrow[r] = __shfl(lacc[r], lane & 48, 64);

    #pragma unroll
    for (int dt = 0; dt < 4; ++dt)
      #pragma unroll
      for (int r = 0; r < 4; ++r) {
        int q = q0 + wid * 16 + quad * 4 + r;
        int d = dt * 16 + l16;
        float val = oacc[dt][r] / lrow[r];
        o[((size_t)(b * SEQ + q)) * EMB + h * HDIM + d] = (bf16)val;
      }
  }
}

// ---------------- out projection (unchanged) ----------------

__launch_bounds__(256, 2)
__global__ void gemm_out_kernel(const bf16* __restrict__ oin, const bf16* __restrict__ wt,
                                float* __restrict__ out) {
  __shared__ __align__(16) bf16 As_[128 * 64];
  __shared__ __align__(16) bf16 Bs_[128 * 64];
  const int tid = threadIdx.x;
  const int lane = tid & 63, wid = tid >> 6;
  const int quad = lane >> 4, l16 = lane & 15;
  const int m0 = blockIdx.x * 128, n0 = blockIdx.y * 128;
  const int wm = (wid >> 1) * 64, wn = (wid & 1) * 64;
  f32v4 acc[4][4] = {};

  for (int kt = 0; kt < EMB / 64; ++kt) {
    __syncthreads();
    #pragma unroll
    for (int r = 0; r < 4; ++r) {
      int li = r * 256 + tid;
      int row = li >> 3, col = (li & 7) * 8;
      gload_lds16(oin + (size_t)(m0 + row) * EMB + kt * 64 + col, &As_[li * 8]);
      gload_lds16(wt  + (size_t)(n0 + row) * EMB + kt * 64 + col, &Bs_[li * 8]);
    }
    __syncthreads();
    #pragma unroll
    for (int kk = 0; kk < 2; ++kk) {
      bf16v8 af[4], bfr[4];
      #pragma unroll
      for (int i = 0; i < 4; ++i) {
        af[i]  = *(const bf16v8*)&As_[(wm + i * 16 + l16) * 64 + kk * 32 + quad * 8];
        bfr[i] = *(const bf16v8*)&Bs_[(wn + i * 16 + l16) * 64 + kk * 32 + quad * 8];
      }
      #pragma unroll
      for (int i = 0; i < 4; ++i)
        #pragma unroll
        for (int j = 0; j < 4; ++j)
          acc[i][j] = MFMA16(af[i], bfr[j], acc[i][j]);
    }
  }
  #pragma unroll
  for (int i = 0; i < 4; ++i)
    #pragma unroll
    for (int j = 0; j < 4; ++j)
      #pragma unroll
      for (int r = 0; r < 4; ++r) {
        int m = m0 + wm + i * 16 + quad * 4 + r;
        int n = n0 + wn + j * 16 + l16;
        out[(size_t)m * EMB + n] = acc[i][j][r];
      }
}

// ---------------- launch ----------------

extern "C" void kernel_launch(void* const* d_in, const int* in_sizes, int n_in,
                              void* d_out, int out_size, void* d_ws, size_t ws_size,
                              hipStream_t stream) {
  const float* x     = (const float*)d_in[0];
  const float* w_qkv = (const float*)d_in[1];
  const float* w_out = (const float*)d_in[2];
  float* out = (float*)d_out;
  char* ws = (char*)d_ws;

  const size_t SZ  = (size_t)MROWS * EMB * sizeof(bf16);   // 16.78 MB
  const size_t SZ8 = (size_t)MROWS * EMB;                  // 8.39 MB (i8 plane)
  size_t off = 0;
  float* sums = (float*)ws;            off = 256;
  char*  wq8  = (char*)(ws + off);     off += (size_t)NQKV * EMB;               // 3.1 MB
  bf16*  wo_t = (bf16*)(ws + off);     off += (size_t)EMB * EMB * sizeof(bf16); // 2.1 MB
  char*  xq1  = (char*)(ws + off);     off += SZ8;
  char*  xq2  = (char*)(ws + off);     off += SZ8;
  bf16*  qh   = (bf16*)(ws + off);     off += SZ;
  bf16*  ql   = (bf16*)(ws + off);     off += SZ;
  bf16*  kh   = (bf16*)(ws + off);     off += SZ;
  bf16*  kl   = (bf16*)(ws + off);     off += SZ;
  bf16*  vv   = (bf16*)(ws + off);     off += SZ;
  bf16*  vt   = (bf16*)xq1;   // x planes dead after gemm_qkv -> 16.8 MB spans xq1+xq2
  bf16*  ob   = vv;           // vv dead after transpose; attn writes ob
  (void)in_sizes; (void)n_in; (void)out_size; (void)ws_size;

  zero2_kernel<<<1, 2, 0, stream>>>(sums);
  abs_sum_kernel<<<256, 256, 0, stream>>>(w_qkv, NQKV * EMB, &sums[0]);
  abs_sum_kernel<<<256, 256, 0, stream>>>(w_out, EMB * EMB, &sums[1]);
  ternarize_i8_kernel<<<(NQKV * EMB) / 256, 256, 0, stream>>>(w_qkv, NQKV * EMB, &sums[0], wq8);
  ternarize_bf16_kernel<<<(EMB * EMB) / 256, 256, 0, stream>>>(w_out, EMB * EMB, &sums[1], wo_t);
  quant_x_kernel<<<(MROWS * EMB) / 256, 256, 0, stream>>>(x, xq1, xq2, MROWS * EMB);
  gemm_qkv_kernel<<<dim3(MROWS / 128, NQKV / 128), 256, 0, stream>>>(xq1, xq2, wq8, qh, ql, kh, kl, vv);
  transpose_v_kernel<<<dim3(SEQ / 64, BSZ * NHEAD), 256, 0, stream>>>(vv, vt);
  attn_kernel<<<dim3(8, BSZ * NHEAD), 512, 0, stream>>>(qh, ql, kh, kl, vt, ob);
  gemm_out_kernel<<<dim3(MROWS / 128, EMB / 128), 256, 0, stream>>>(ob, wo_t, out);
}